// Round 1
// baseline (4617.816 us; speedup 1.0000x reference)
//
#include <hip/hip_runtime.h>
#include <math.h>

// Problem constants
#define B_      64
#define L_      256
#define V_      30000
#define E_      300
#define H_      200
#define G4_     800     // 4*H
#define ENC_    400
#define NH_     4
#define DH_     100
#define SCALING_ 1000.0f

__device__ __forceinline__ float sigmoidf_(float x) { return 1.0f / (1.0f + expf(-x)); }

// ---------------- block reductions (256 threads = 4 waves) ----------------
__device__ __forceinline__ float blockSum256(float v, float* red) {
    for (int off = 32; off > 0; off >>= 1) v += __shfl_down(v, off);
    __syncthreads();
    if ((threadIdx.x & 63) == 0) red[threadIdx.x >> 6] = v;
    __syncthreads();
    return red[0] + red[1] + red[2] + red[3];
}
__device__ __forceinline__ float blockMax256(float v, float* red) {
    for (int off = 32; off > 0; off >>= 1) v = fmaxf(v, __shfl_down(v, off));
    __syncthreads();
    if ((threadIdx.x & 63) == 0) red[threadIdx.x >> 6] = v;
    __syncthreads();
    return fmaxf(fmaxf(red[0], red[1]), fmaxf(red[2], red[3]));
}

// ---------------- prep: lengths + budget ----------------
// mask dtype is ambiguous (bool-bytes vs int32). lengths >= L/2 = 128, so
// mask[0][1] is always true: byte 1 of the buffer is 1 for byte-rep, 0 for
// int32-rep (little-endian). Nonzero-word test works for int32/float reps.
__global__ void k_prep(const void* __restrict__ maskraw, int* __restrict__ lengths,
                       float* __restrict__ budget) {
    int b = blockIdx.x;
    const unsigned char* mb = (const unsigned char*)maskraw;
    bool is_byte = (mb[1] != 0);
    const int* mi = (const int*)maskraw;
    int cnt = 0;
    for (int l = threadIdx.x; l < L_; l += 64) {
        int v = is_byte ? (int)mb[b * L_ + l] : mi[b * L_ + l];
        cnt += (v != 0) ? 1 : 0;
    }
    for (int off = 32; off > 0; off >>= 1) cnt += __shfl_down(cnt, off);
    if (threadIdx.x == 0) {
        lengths[b] = cnt;
        budget[b] = rintf(0.2f * (float)cnt);   // jnp.round = half-even = rintf
    }
}

// ---------------- w2 = Wo @ out_W  (400 dots of 400) ----------------
__global__ void k_w2(const float* __restrict__ Wo, const float* __restrict__ outW,
                     float* __restrict__ w2) {
    int e = blockIdx.x * blockDim.x + threadIdx.x;
    if (e >= ENC_) return;
    float s = 0.0f;
    for (int j = 0; j < ENC_; j++) s = fmaf(Wo[(size_t)e * ENC_ + j], outW[j], s);
    w2[e] = s;
}

// ---------------- Weff[e*8+c]: c<4 -> Wq_eff (Wk·q), c>=4 -> Wv_eff (Wv·w2) ----------------
__global__ void k_weff(const float* __restrict__ Wk, const float* __restrict__ Wv,
                       const float* __restrict__ q, const float* __restrict__ w2,
                       float* __restrict__ Weff) {
    int idx = blockIdx.x * blockDim.x + threadIdx.x;
    if (idx >= ENC_ * 8) return;
    int e = idx >> 3, c = idx & 7;
    int h = c & 3;
    bool isV = (c >= 4);
    const float* M = isV ? Wv : Wk;
    float s = 0.0f;
    for (int d = 0; d < DH_; d++) {
        float wq = isV ? w2[h * DH_ + d] : q[h * DH_ + d];
        s = fmaf(M[(size_t)e * ENC_ + h * DH_ + d], wq, s);
    }
    Weff[idx] = s;
}

// ---------------- xproj GEMM: (16384 x 300) gathered-emb @ (300 x 1600) + bias ----------------
#define TM 64
#define TN 64
#define KC 16
__global__ __launch_bounds__(256) void k_gemm_xproj(const int* __restrict__ x,
        const float* __restrict__ embW,
        const float* __restrict__ Wi_f, const float* __restrict__ b_f,
        const float* __restrict__ Wi_b, const float* __restrict__ b_b,
        float* __restrict__ xproj) {
    __shared__ float sA[KC][TM + 1];   // +1 pad: transposed stores conflict-free
    __shared__ float sB[KC][TN];
    __shared__ int srow[TM];
    int tid = threadIdx.x;
    int tm0 = blockIdx.x * TM;
    int tn0 = blockIdx.y * TN;
    if (tid < TM) srow[tid] = x[tm0 + tid];
    __syncthreads();
    int tx = tid & 15, ty = tid >> 4;
    float acc[4][4];
#pragma unroll
    for (int u = 0; u < 4; u++)
#pragma unroll
        for (int v = 0; v < 4; v++) acc[u][v] = 0.0f;

    for (int k0 = 0; k0 < E_; k0 += KC) {
        // A tile: 16 consecutive k of one emb row per 16-lane group (coalesced 64B)
#pragma unroll
        for (int i0 = 0; i0 < (TM * KC) / 256; i0++) {
            int i = i0 * 256 + tid;
            int mm = i / KC, kk = i % KC;
            int k = k0 + kk;
            sA[kk][mm] = (k < E_) ? embW[(size_t)srow[mm] * E_ + k] : 0.0f;
        }
        // B tile: consecutive lanes -> consecutive cols (coalesced)
#pragma unroll
        for (int i0 = 0; i0 < (KC * TN) / 256; i0++) {
            int i = i0 * 256 + tid;
            int kk = i / TN, nn = i % TN;
            int k = k0 + kk;
            int col = tn0 + nn;
            float v = 0.0f;
            if (k < E_)
                v = (col < G4_) ? Wi_f[(size_t)k * G4_ + col]
                                : Wi_b[(size_t)k * G4_ + (col - G4_)];
            sB[kk][nn] = v;
        }
        __syncthreads();
#pragma unroll
        for (int kk = 0; kk < KC; kk++) {
            float av[4], bv[4];
#pragma unroll
            for (int u = 0; u < 4; u++) av[u] = sA[kk][ty * 4 + u];
#pragma unroll
            for (int v = 0; v < 4; v++) bv[v] = sB[kk][tx * 4 + v];
#pragma unroll
            for (int u = 0; u < 4; u++)
#pragma unroll
                for (int v = 0; v < 4; v++) acc[u][v] = fmaf(av[u], bv[v], acc[u][v]);
        }
        __syncthreads();
    }
#pragma unroll
    for (int u = 0; u < 4; u++) {
        int m = tm0 + ty * 4 + u;
#pragma unroll
        for (int v = 0; v < 4; v++) {
            int col = tn0 + tx * 4 + v;
            float bias = (col < G4_) ? b_f[col] : b_b[col - G4_];
            xproj[(size_t)m * 1600 + col] = acc[u][v] + bias;
        }
    }
}

// ---------------- biLSTM: one block per (b, dir) chain ----------------
// thread j < 200 owns hidden unit j: computes gate quad (i,f,g,o)[j] and
// updates c_j, h_j with no intra-step gate exchange. h double-buffered in LDS.
// First LDS_ROWS rows of Wh cached in LDS (static-LDS <= 64KB); rest from L2.
#define LDS_ROWS 19
__global__ __launch_bounds__(256) void k_lstm(const float* __restrict__ xproj,
        const float* __restrict__ Wh_f, const float* __restrict__ Wh_b,
        const int* __restrict__ lengths,
        float* __restrict__ hf, float* __restrict__ hb) {
    int chain = blockIdx.x;               // 0..127
    int b = chain >> 1, dir = chain & 1;
    const float* Wh = dir ? Wh_b : Wh_f;
    float* hout = dir ? hb : hf;
    int len = lengths[b];
    __shared__ float sWh[LDS_ROWS * G4_]; // 60,800 B
    __shared__ float sh[2][H_];
    int tid = threadIdx.x;
    for (int i = tid; i < LDS_ROWS * G4_; i += 256) sWh[i] = Wh[i];
    if (tid < H_) sh[0][tid] = 0.0f;
    float c = 0.0f;
    __syncthreads();
    const float* xp = xproj + ((size_t)b * L_) * 1600 + dir * G4_;
    int cur = 0;
    for (int s = 0; s < L_; s++) {
        int t = dir ? (L_ - 1 - s) : s;
        if (tid < H_) {
            const float* xr = xp + (size_t)t * 1600;
            float ai = xr[tid], af = xr[H_ + tid], ag = xr[2 * H_ + tid], ao = xr[3 * H_ + tid];
            const float* hc = sh[cur];
#pragma unroll 4
            for (int k = 0; k < LDS_ROWS; k++) {
                float hk = hc[k];
                const float* wr = &sWh[k * G4_];
                ai = fmaf(hk, wr[tid], ai);
                af = fmaf(hk, wr[H_ + tid], af);
                ag = fmaf(hk, wr[2 * H_ + tid], ag);
                ao = fmaf(hk, wr[3 * H_ + tid], ao);
            }
#pragma unroll 4
            for (int k = LDS_ROWS; k < H_; k++) {
                float hk = hc[k];
                const float* wr = Wh + (size_t)k * G4_;
                ai = fmaf(hk, wr[tid], ai);
                af = fmaf(hk, wr[H_ + tid], af);
                ag = fmaf(hk, wr[2 * H_ + tid], ag);
                ao = fmaf(hk, wr[3 * H_ + tid], ao);
            }
            float hv;
            if (t < len) {
                float ii = sigmoidf_(ai), ff = sigmoidf_(af);
                float gg = tanhf(ag), oo = sigmoidf_(ao);
                c = ff * c + ii * gg;
                hv = oo * tanhf(c);
            } else {
                hv = hc[tid];   // masked step: h (and c) unchanged
            }
            sh[cur ^ 1][tid] = hv;
            hout[((size_t)b * L_ + t) * H_ + tid] = hv;
        }
        __syncthreads();
        cur ^= 1;
    }
}

// ---------------- scores + vproj: h1 @ Weff (400 x 8) ----------------
__global__ __launch_bounds__(256) void k_proj(const float* __restrict__ hf,
        const float* __restrict__ hb, const float* __restrict__ Weff,
        float* __restrict__ scores, float* __restrict__ vproj) {
    __shared__ float sW[ENC_ * 8];
    int tid = threadIdx.x;
    for (int i = tid; i < ENC_ * 8; i += 256) sW[i] = Weff[i];
    __syncthreads();
    int pos = blockIdx.x * 32 + (tid >> 3);   // 512 blocks x 32 positions
    int o = tid & 7;
    int b = pos >> 8, l = pos & 255;
    const float* hfr = hf + (size_t)pos * H_;
    const float* hbr = hb + (size_t)pos * H_;
    float s = 0.0f;
#pragma unroll 4
    for (int e = 0; e < H_; e++) s = fmaf(hfr[e], sW[e * 8 + o], s);
#pragma unroll 4
    for (int e = 0; e < H_; e++) s = fmaf(hbr[e], sW[(H_ + e) * 8 + o], s);
    if (o < NH_) scores[((size_t)b * NH_ + o) * L_ + l] = SCALING_ * s;
    else        vproj[(size_t)pos * NH_ + (o - NH_)] = s;
}

// ---------------- budget projection: one block per (b,h) ----------------
__global__ __launch_bounds__(256) void k_budget(const float* __restrict__ scores,
        const int* __restrict__ lengths, const float* __restrict__ budget,
        float* __restrict__ p) {
    __shared__ float red[4];
    int bh = blockIdx.x;
    int b = bh >> 2;
    int l = threadIdx.x;
    int len = lengths[b];
    float bud = budget[b];
    bool m = (l < len);
    float s = m ? scores[(size_t)bh * L_ + l] : -1.0e9f;
    float p0 = fminf(fmaxf(s, 0.0f), 1.0f);
    float sum_p0 = blockSum256(p0, red);
    bool need = (sum_p0 > bud);
    float hi = blockMax256(m ? s : 0.0f, red) + 1.0f;
    float lo = 0.0f;
    for (int it = 0; it < 60; it++) {
        float mid = 0.5f * (lo + hi);
        float val = blockSum256(fminf(fmaxf(s - mid, 0.0f), 1.0f), red);
        if (val > bud) lo = mid; else hi = mid;   // uniform across block
    }
    float tau0 = 0.5f * (lo + hi);
    float r = s - tau0;
    bool fr  = (r > 0.0f) && (r < 1.0f) && m;
    bool h1f = (r >= 1.0f) && m;
    float n_free   = blockSum256(fr ? 1.0f : 0.0f, red);
    float sum_free = blockSum256(fr ? s : 0.0f, red);
    float n_hi     = blockSum256(h1f ? 1.0f : 0.0f, red);
    float tau = (sum_free + n_hi - bud) / fmaxf(n_free, 1.0f);
    tau = (n_free > 0.0f) ? tau : tau0;
    float pv = fminf(fmaxf(s - tau, 0.0f), 1.0f);
    p[(size_t)bh * L_ + l] = need ? pv : p0;
}

// ---------------- finalize: y[b] and zp[b,l] ----------------
__global__ __launch_bounds__(256) void k_final(const float* __restrict__ p,
        const float* __restrict__ vproj, const int* __restrict__ lengths,
        const float* __restrict__ out_b, float* __restrict__ dout) {
    __shared__ float red[4];
    int b = blockIdx.x;
    int l = threadIdx.x;
    int len = lengths[b];
    float p0 = p[((size_t)b * NH_ + 0) * L_ + l];
    float p1 = p[((size_t)b * NH_ + 1) * L_ + l];
    float p2 = p[((size_t)b * NH_ + 2) * L_ + l];
    float p3 = p[((size_t)b * NH_ + 3) * L_ + l];
    dout[B_ + (size_t)b * L_ + l] = (l < len) ? 0.25f * (p0 + p1 + p2 + p3) : 0.0f;
    const float* vp = vproj + ((size_t)b * L_ + l) * NH_;
    float contrib = p0 * vp[0] + p1 * vp[1] + p2 * vp[2] + p3 * vp[3];
    float tot = blockSum256(contrib, red);
    if (l == 0) dout[b] = 1.0f / (1.0f + expf(-(tot + out_b[0])));
}

// ---------------- launch ----------------
extern "C" void kernel_launch(void* const* d_in, const int* in_sizes, int n_in,
                              void* d_out, int out_size, void* d_ws, size_t ws_size,
                              hipStream_t stream) {
    const int*   x    = (const int*)d_in[0];
    // d_in[1] (z) is unused by the reference
    const void*  mask = d_in[2];
    const float* embW = (const float*)d_in[3];
    const float* Wi_f = (const float*)d_in[4];
    const float* Wh_f = (const float*)d_in[5];
    const float* b_f  = (const float*)d_in[6];
    const float* Wi_b = (const float*)d_in[7];
    const float* Wh_b = (const float*)d_in[8];
    const float* b_b  = (const float*)d_in[9];
    const float* Wk   = (const float*)d_in[10];
    const float* Wv   = (const float*)d_in[11];
    const float* q    = (const float*)d_in[12];
    const float* Wo   = (const float*)d_in[13];
    const float* outW = (const float*)d_in[14];
    const float* outb = (const float*)d_in[15];
    float* dout = (float*)d_out;

    // workspace layout (floats); total ~32.97M floats ~ 132 MB
    float* ws     = (float*)d_ws;
    float* xproj  = ws;                               // 16384*1600 = 26,214,400
    float* hf     = xproj + (size_t)16384 * 1600;     // 3,276,800
    float* hb     = hf + (size_t)16384 * 200;         // 3,276,800
    float* scores = hb + (size_t)16384 * 200;         // 65,536
    float* vproj  = scores + 65536;                   // 65,536
    float* p      = vproj + 65536;                    // 65,536
    float* Weff   = p + 65536;                        // 3,200
    float* w2     = Weff + 3200;                      // 400
    float* budget = w2 + 400;                         // 64
    int*   lengths= (int*)(budget + 64);              // 64

    k_prep<<<B_, 64, 0, stream>>>(mask, lengths, budget);
    k_w2<<<2, 256, 0, stream>>>(Wo, outW, w2);
    k_weff<<<13, 256, 0, stream>>>(Wk, Wv, q, w2, Weff);
    k_gemm_xproj<<<dim3(16384 / TM, 1600 / TN), 256, 0, stream>>>(x, embW, Wi_f, b_f, Wi_b, b_b, xproj);
    k_lstm<<<128, 256, 0, stream>>>(xproj, Wh_f, Wh_b, lengths, hf, hb);
    k_proj<<<(B_ * L_) / 32, 256, 0, stream>>>(hf, hb, Weff, scores, vproj);
    k_budget<<<B_ * NH_, 256, 0, stream>>>(scores, lengths, budget, p);
    k_final<<<B_, 256, 0, stream>>>(p, vproj, lengths, outb, dout);
}

// Round 2
// 2085.554 us; speedup vs baseline: 2.2142x; 2.2142x over previous
//
#include <hip/hip_runtime.h>
#include <math.h>

// Problem constants
#define B_      64
#define L_      256
#define V_      30000
#define E_      300
#define H_      200
#define G4_     800     // 4*H
#define ENC_    400
#define NH_     4
#define DH_     100
#define SCALING_ 1000.0f

__device__ __forceinline__ float sigmoidf_(float x) { return 1.0f / (1.0f + expf(-x)); }

// ---------------- block reductions (256 threads = 4 waves) ----------------
__device__ __forceinline__ float blockSum256(float v, float* red) {
    for (int off = 32; off > 0; off >>= 1) v += __shfl_down(v, off);
    __syncthreads();
    if ((threadIdx.x & 63) == 0) red[threadIdx.x >> 6] = v;
    __syncthreads();
    return red[0] + red[1] + red[2] + red[3];
}
__device__ __forceinline__ float blockMax256(float v, float* red) {
    for (int off = 32; off > 0; off >>= 1) v = fmaxf(v, __shfl_down(v, off));
    __syncthreads();
    if ((threadIdx.x & 63) == 0) red[threadIdx.x >> 6] = v;
    __syncthreads();
    return fmaxf(fmaxf(red[0], red[1]), fmaxf(red[2], red[3]));
}

// ---------------- prep: lengths + budget ----------------
__global__ void k_prep(const void* __restrict__ maskraw, int* __restrict__ lengths,
                       float* __restrict__ budget) {
    int b = blockIdx.x;
    const unsigned char* mb = (const unsigned char*)maskraw;
    bool is_byte = (mb[1] != 0);
    const int* mi = (const int*)maskraw;
    int cnt = 0;
    for (int l = threadIdx.x; l < L_; l += 64) {
        int v = is_byte ? (int)mb[b * L_ + l] : mi[b * L_ + l];
        cnt += (v != 0) ? 1 : 0;
    }
    for (int off = 32; off > 0; off >>= 1) cnt += __shfl_down(cnt, off);
    if (threadIdx.x == 0) {
        lengths[b] = cnt;
        budget[b] = rintf(0.2f * (float)cnt);
    }
}

// ---------------- w2 = Wo @ out_W ----------------
__global__ void k_w2(const float* __restrict__ Wo, const float* __restrict__ outW,
                     float* __restrict__ w2) {
    int e = blockIdx.x * blockDim.x + threadIdx.x;
    if (e >= ENC_) return;
    float s = 0.0f;
    for (int j = 0; j < ENC_; j++) s = fmaf(Wo[(size_t)e * ENC_ + j], outW[j], s);
    w2[e] = s;
}

// ---------------- Weff ----------------
__global__ void k_weff(const float* __restrict__ Wk, const float* __restrict__ Wv,
                       const float* __restrict__ q, const float* __restrict__ w2,
                       float* __restrict__ Weff) {
    int idx = blockIdx.x * blockDim.x + threadIdx.x;
    if (idx >= ENC_ * 8) return;
    int e = idx >> 3, c = idx & 7;
    int h = c & 3;
    bool isV = (c >= 4);
    const float* M = isV ? Wv : Wk;
    float s = 0.0f;
    for (int d = 0; d < DH_; d++) {
        float wq = isV ? w2[h * DH_ + d] : q[h * DH_ + d];
        s = fmaf(M[(size_t)e * ENC_ + h * DH_ + d], wq, s);
    }
    Weff[idx] = s;
}

// ---------------- pack Wh gate-interleaved: Wp[dir][k][j][g] = Wh[k][g*H+j] ----------------
__global__ void k_pack(const float* __restrict__ Wh_f, const float* __restrict__ Wh_b,
                       float* __restrict__ Wp) {
    int idx = blockIdx.x * 256 + threadIdx.x;   // over 2*200*200*4 = 320000
    if (idx >= 2 * H_ * H_ * 4) return;
    int dir = idx / (H_ * H_ * 4);
    int r = idx % (H_ * H_ * 4);
    int k = r / (H_ * 4);
    int r2 = r % (H_ * 4);
    int j = r2 >> 2, g = r2 & 3;
    const float* Wh = dir ? Wh_b : Wh_f;
    Wp[idx] = Wh[(size_t)k * G4_ + g * H_ + j];
}

// ---------------- xproj GEMM ----------------
#define TM 64
#define TN 64
#define KC 16
__global__ __launch_bounds__(256) void k_gemm_xproj(const int* __restrict__ x,
        const float* __restrict__ embW,
        const float* __restrict__ Wi_f, const float* __restrict__ b_f,
        const float* __restrict__ Wi_b, const float* __restrict__ b_b,
        float* __restrict__ xproj) {
    __shared__ float sA[KC][TM + 1];
    __shared__ float sB[KC][TN];
    __shared__ int srow[TM];
    int tid = threadIdx.x;
    int tm0 = blockIdx.x * TM;
    int tn0 = blockIdx.y * TN;
    if (tid < TM) srow[tid] = x[tm0 + tid];
    __syncthreads();
    int tx = tid & 15, ty = tid >> 4;
    float acc[4][4];
#pragma unroll
    for (int u = 0; u < 4; u++)
#pragma unroll
        for (int v = 0; v < 4; v++) acc[u][v] = 0.0f;

    for (int k0 = 0; k0 < E_; k0 += KC) {
#pragma unroll
        for (int i0 = 0; i0 < (TM * KC) / 256; i0++) {
            int i = i0 * 256 + tid;
            int mm = i / KC, kk = i % KC;
            int k = k0 + kk;
            sA[kk][mm] = (k < E_) ? embW[(size_t)srow[mm] * E_ + k] : 0.0f;
        }
#pragma unroll
        for (int i0 = 0; i0 < (KC * TN) / 256; i0++) {
            int i = i0 * 256 + tid;
            int kk = i / TN, nn = i % TN;
            int k = k0 + kk;
            int col = tn0 + nn;
            float v = 0.0f;
            if (k < E_)
                v = (col < G4_) ? Wi_f[(size_t)k * G4_ + col]
                                : Wi_b[(size_t)k * G4_ + (col - G4_)];
            sB[kk][nn] = v;
        }
        __syncthreads();
#pragma unroll
        for (int kk = 0; kk < KC; kk++) {
            float av[4], bv[4];
#pragma unroll
            for (int u = 0; u < 4; u++) av[u] = sA[kk][ty * 4 + u];
#pragma unroll
            for (int v = 0; v < 4; v++) bv[v] = sB[kk][tx * 4 + v];
#pragma unroll
            for (int u = 0; u < 4; u++)
#pragma unroll
                for (int v = 0; v < 4; v++) acc[u][v] = fmaf(av[u], bv[v], acc[u][v]);
        }
        __syncthreads();
    }
#pragma unroll
    for (int u = 0; u < 4; u++) {
        int m = tm0 + ty * 4 + u;
#pragma unroll
        for (int v = 0; v < 4; v++) {
            int col = tn0 + tx * 4 + v;
            float bias = (col < G4_) ? b_f[col] : b_b[col - G4_];
            xproj[(size_t)m * 1600 + col] = acc[u][v] + bias;
        }
    }
}

// ---------------- biLSTM v2: 128 blocks x 1024 threads, k split 4 ways ----------------
// thread (q, j): partial gates for hidden unit j over rows k in [50q, 50q+50).
// Weights read as float4 (gate-interleaved pack). Partials reduced via LDS.
// Only `len` steps run (t<len is block-uniform; mask is a prefix); frozen tail
// rows bulk-written after (forward: h_{len-1}, backward: 0).
__global__ __launch_bounds__(1024, 4) void k_lstm(const float* __restrict__ xproj,
        const float4* __restrict__ Wp, const int* __restrict__ lengths,
        float* __restrict__ hf, float* __restrict__ hb) {
    int chain = blockIdx.x;               // 0..127
    int b = chain >> 1, dir = chain & 1;
    const float4* W = Wp + (size_t)dir * H_ * H_;   // [k][j] float4
    float* hout = dir ? hb : hf;
    int len = lengths[b];
    __shared__ float sh[H_];
    __shared__ float4 sPart[4][256];      // [q][j], 16 KB
    int tid = threadIdx.x;
    int j = tid & 255, q = tid >> 8;
    bool act = (j < H_);
    if (tid < H_) sh[tid] = 0.0f;
    float c = 0.0f;
    __syncthreads();
    const float* xp = xproj + (size_t)b * L_ * 1600 + dir * G4_;
    const float4* wp = W + (size_t)q * 50 * H_ + j;
    const float* hq = sh + q * 50;

    for (int s = 0; s < len; s++) {
        int t = dir ? (len - 1 - s) : s;
        if (act) {
            const float* xr = xp + (size_t)t * 1600;
            float xv = xr[q * H_ + j];
            float4 acc;
            acc.x = acc.y = acc.z = acc.w = 0.0f;
#pragma unroll 10
            for (int k = 0; k < 50; k++) {
                float hk = hq[k];                 // LDS broadcast within group
                float4 w = wp[(size_t)k * H_];    // global_load_dwordx4 (L2)
                acc.x = fmaf(hk, w.x, acc.x);
                acc.y = fmaf(hk, w.y, acc.y);
                acc.z = fmaf(hk, w.z, acc.z);
                acc.w = fmaf(hk, w.w, acc.w);
            }
            if (q == 0) acc.x += xv;
            else if (q == 1) acc.y += xv;
            else if (q == 2) acc.z += xv;
            else acc.w += xv;
            sPart[q][j] = acc;
        }
        __syncthreads();
        if (tid < H_) {
            float4 p0 = sPart[0][tid], p1 = sPart[1][tid];
            float4 p2 = sPart[2][tid], p3 = sPart[3][tid];
            float ai = p0.x + p1.x + p2.x + p3.x;
            float af = p0.y + p1.y + p2.y + p3.y;
            float ag = p0.z + p1.z + p2.z + p3.z;
            float ao = p0.w + p1.w + p2.w + p3.w;
            float ii = sigmoidf_(ai), ff = sigmoidf_(af);
            float gg = tanhf(ag), oo = sigmoidf_(ao);
            c = ff * c + ii * gg;
            float hv = oo * tanhf(c);
            sh[tid] = hv;
            hout[((size_t)b * L_ + t) * H_ + tid] = hv;
        }
        __syncthreads();
    }
    // frozen tail t in [len, 256): forward -> h_{len-1} (= sh), backward -> 0
    for (int i = tid; i < (L_ - len) * H_; i += 1024) {
        int t = len + i / H_, u = i % H_;
        hout[((size_t)b * L_ + t) * H_ + u] = dir ? 0.0f : sh[u];
    }
}

// ---------------- scores + vproj ----------------
__global__ __launch_bounds__(256) void k_proj(const float* __restrict__ hf,
        const float* __restrict__ hb, const float* __restrict__ Weff,
        float* __restrict__ scores, float* __restrict__ vproj) {
    __shared__ float sW[ENC_ * 8];
    int tid = threadIdx.x;
    for (int i = tid; i < ENC_ * 8; i += 256) sW[i] = Weff[i];
    __syncthreads();
    int pos = blockIdx.x * 32 + (tid >> 3);
    int o = tid & 7;
    int b = pos >> 8, l = pos & 255;
    const float* hfr = hf + (size_t)pos * H_;
    const float* hbr = hb + (size_t)pos * H_;
    float s = 0.0f;
#pragma unroll 4
    for (int e = 0; e < H_; e++) s = fmaf(hfr[e], sW[e * 8 + o], s);
#pragma unroll 4
    for (int e = 0; e < H_; e++) s = fmaf(hbr[e], sW[(H_ + e) * 8 + o], s);
    if (o < NH_) scores[((size_t)b * NH_ + o) * L_ + l] = SCALING_ * s;
    else        vproj[(size_t)pos * NH_ + (o - NH_)] = s;
}

// ---------------- budget projection ----------------
__global__ __launch_bounds__(256) void k_budget(const float* __restrict__ scores,
        const int* __restrict__ lengths, const float* __restrict__ budget,
        float* __restrict__ p) {
    __shared__ float red[4];
    int bh = blockIdx.x;
    int b = bh >> 2;
    int l = threadIdx.x;
    int len = lengths[b];
    float bud = budget[b];
    bool m = (l < len);
    float s = m ? scores[(size_t)bh * L_ + l] : -1.0e9f;
    float p0 = fminf(fmaxf(s, 0.0f), 1.0f);
    float sum_p0 = blockSum256(p0, red);
    bool need = (sum_p0 > bud);
    float hi = blockMax256(m ? s : 0.0f, red) + 1.0f;
    float lo = 0.0f;
    for (int it = 0; it < 60; it++) {
        float mid = 0.5f * (lo + hi);
        float val = blockSum256(fminf(fmaxf(s - mid, 0.0f), 1.0f), red);
        if (val > bud) lo = mid; else hi = mid;
    }
    float tau0 = 0.5f * (lo + hi);
    float r = s - tau0;
    bool fr  = (r > 0.0f) && (r < 1.0f) && m;
    bool h1f = (r >= 1.0f) && m;
    float n_free   = blockSum256(fr ? 1.0f : 0.0f, red);
    float sum_free = blockSum256(fr ? s : 0.0f, red);
    float n_hi     = blockSum256(h1f ? 1.0f : 0.0f, red);
    float tau = (sum_free + n_hi - bud) / fmaxf(n_free, 1.0f);
    tau = (n_free > 0.0f) ? tau : tau0;
    float pv = fminf(fmaxf(s - tau, 0.0f), 1.0f);
    p[(size_t)bh * L_ + l] = need ? pv : p0;
}

// ---------------- finalize ----------------
__global__ __launch_bounds__(256) void k_final(const float* __restrict__ p,
        const float* __restrict__ vproj, const int* __restrict__ lengths,
        const float* __restrict__ out_b, float* __restrict__ dout) {
    __shared__ float red[4];
    int b = blockIdx.x;
    int l = threadIdx.x;
    int len = lengths[b];
    float p0 = p[((size_t)b * NH_ + 0) * L_ + l];
    float p1 = p[((size_t)b * NH_ + 1) * L_ + l];
    float p2 = p[((size_t)b * NH_ + 2) * L_ + l];
    float p3 = p[((size_t)b * NH_ + 3) * L_ + l];
    dout[B_ + (size_t)b * L_ + l] = (l < len) ? 0.25f * (p0 + p1 + p2 + p3) : 0.0f;
    const float* vp = vproj + ((size_t)b * L_ + l) * NH_;
    float contrib = p0 * vp[0] + p1 * vp[1] + p2 * vp[2] + p3 * vp[3];
    float tot = blockSum256(contrib, red);
    if (l == 0) dout[b] = 1.0f / (1.0f + expf(-(tot + out_b[0])));
}

// ---------------- launch ----------------
extern "C" void kernel_launch(void* const* d_in, const int* in_sizes, int n_in,
                              void* d_out, int out_size, void* d_ws, size_t ws_size,
                              hipStream_t stream) {
    const int*   x    = (const int*)d_in[0];
    const void*  mask = d_in[2];
    const float* embW = (const float*)d_in[3];
    const float* Wi_f = (const float*)d_in[4];
    const float* Wh_f = (const float*)d_in[5];
    const float* b_f  = (const float*)d_in[6];
    const float* Wi_b = (const float*)d_in[7];
    const float* Wh_b = (const float*)d_in[8];
    const float* b_b  = (const float*)d_in[9];
    const float* Wk   = (const float*)d_in[10];
    const float* Wv   = (const float*)d_in[11];
    const float* q    = (const float*)d_in[12];
    const float* Wo   = (const float*)d_in[13];
    const float* outW = (const float*)d_in[14];
    const float* outb = (const float*)d_in[15];
    float* dout = (float*)d_out;

    float* ws     = (float*)d_ws;
    float* xproj  = ws;                               // 26,214,400
    float* hf     = xproj + (size_t)16384 * 1600;     // 3,276,800
    float* hb     = hf + (size_t)16384 * 200;         // 3,276,800
    float* scores = hb + (size_t)16384 * 200;         // 65,536
    float* vproj  = scores + 65536;                   // 65,536
    float* p      = vproj + 65536;                    // 65,536
    float* Weff   = p + 65536;                        // 3,200
    float* w2     = Weff + 3200;                      // 400
    float* budget = w2 + 400;                         // 64
    int*   lengths= (int*)(budget + 64);              // 64
    float* Wp     = (float*)(lengths + 64);           // 320,000 packed Wh

    k_prep<<<B_, 64, 0, stream>>>(mask, lengths, budget);
    k_w2<<<2, 256, 0, stream>>>(Wo, outW, w2);
    k_weff<<<13, 256, 0, stream>>>(Wk, Wv, q, w2, Weff);
    k_pack<<<(2 * H_ * H_ * 4 + 255) / 256, 256, 0, stream>>>(Wh_f, Wh_b, Wp);
    k_gemm_xproj<<<dim3(16384 / TM, 1600 / TN), 256, 0, stream>>>(x, embW, Wi_f, b_f, Wi_b, b_b, xproj);
    k_lstm<<<128, 1024, 0, stream>>>(xproj, (const float4*)Wp, lengths, hf, hb);
    k_proj<<<(B_ * L_) / 32, 256, 0, stream>>>(hf, hb, Weff, scores, vproj);
    k_budget<<<B_ * NH_, 256, 0, stream>>>(scores, lengths, budget, p);
    k_final<<<B_, 256, 0, stream>>>(p, vproj, lengths, outb, dout);
}